// Round 6
// baseline (2897.035 us; speedup 1.0000x reference)
//
#include <hip/hip_runtime.h>
#include <cstdint>
#include <cstddef>

#define B_    2
#define N_    8192
#define M_    2048
#define K_    32
#define C0_   64
#define C1_   128
#define C2_   256
#define CIN_  67
#define CHUNK 128
#define NBLK  254          // 2 FPS blocks + 252 MLP blocks (<=256 CUs, 1 blk/CU)
#define FPSB  2
#define MLPB  (NBLK - FPSB)

// Exact-match distance: reference computes sum((a-b)**2, axis=-1) in f32 as
// ((dx^2 + dy^2) + dz^2) with no FMA contraction. _rn intrinsics forbid
// contract-fast fma fusion (would flip argmax / radius-boundary decisions).
__device__ __forceinline__ float sqdist_rn(float ax, float ay, float az,
                                           float bx, float by, float bz) {
  float dx = __fsub_rn(ax, bx);
  float dy = __fsub_rn(ay, by);
  float dz = __fsub_rn(az, bz);
  return __fadd_rn(__fadd_rn(__fmul_rn(dx, dx), __fmul_rn(dy, dy)),
                   __fmul_rn(dz, dz));
}

__device__ __forceinline__ int morton8(int ix, int iy, int iz) {
  int m = 0;
#pragma unroll
  for (int b = 0; b < 3; ++b) {
    m |= (((ix >> b) & 1) << (3 * b + 2)) | (((iy >> b) & 1) << (3 * b + 1)) |
         (((iz >> b) & 1) << (3 * b + 0));
  }
  return m;
}

// u64 max across the wave via paired DPP (row_shr 1/2/4/8, row_bcast 15/31);
// cumulative max lands in lane 63. Exact tie-break is baked into the key.
__device__ __forceinline__ unsigned long long wave_max_u64_dpp(unsigned long long k) {
#define FPS_STEP(ctrl)                                                         \
  {                                                                            \
    int klo = (int)(unsigned)k, khi = (int)(unsigned)(k >> 32);                \
    int olo = __builtin_amdgcn_update_dpp(klo, klo, ctrl, 0xf, 0xf, false);    \
    int ohi = __builtin_amdgcn_update_dpp(khi, khi, ctrl, 0xf, 0xf, false);    \
    unsigned long long ok =                                                    \
        ((unsigned long long)(unsigned)ohi << 32) | (unsigned)olo;             \
    if (ok > k) k = ok;                                                        \
  }
  FPS_STEP(0x111)  // row_shr:1
  FPS_STEP(0x112)  // row_shr:2
  FPS_STEP(0x114)  // row_shr:4
  FPS_STEP(0x118)  // row_shr:8
  FPS_STEP(0x142)  // row_bcast:15
  FPS_STEP(0x143)  // row_bcast:31
#undef FPS_STEP
  return k;
}

// ---------------------------------------------------------------------------
// Shared-memory union: FPS layout (blocks 0-1) vs quad-MLP layout (blocks 2+).
// ---------------------------------------------------------------------------
struct SmemFps {
  float px[N_];                       // 32 KiB sorted x
  float py[N_];                       // 32 KiB sorted y
  float pz[N_];                       // 32 KiB sorted z
  float d[N_];                        // 32 KiB min dists (sort scratch union)
  unsigned short pid[N_];             // 16 KiB original ids
  unsigned long long bkey[N_ / 8];    //  8 KiB per-bucket argmax key
  int wlist[16][64];                  //  4 KiB per-wave dirty lists
  unsigned long long win[3];          // rotating winner slots (mod-3 protocol)
  float recent[CHUNK * 3];            // 1.5 KiB winner ring (row-major [128][3])
};
struct MlpQuarter {
  float GRed[32 * 69];                // group tile; reused as 8x256 max-red
  float H1[32 * 132];
  int WIdx[4][K_];
  int WCnt[4];
  int Idx[K_];
  float Q[4];
};
struct SmemMlp {
  float U[128 * 69];                  // W1 staged; reused as 32x256 W2 tile (shared by quarters)
  MlpQuarter q[4];
};
union SmemU {
  SmemFps f;
  SmemMlp m;
};

// ---------------------------------------------------------------------------
// ONE fused kernel. Blocks 0-1: FPS (R4 core, 2317 us — best measured) with
// a 128-row LDS winner ring flushed to new_xyz once per CHUNK iters followed
// by threadfence + agent-release of progress[b] (release lags one chunk so
// flush stores are provably drained by 128 intervening barrier vmcnt-drains;
// in-loop per-iter global stores were proven poison in R3). Blocks 2-253:
// 4x the proven 256-thread MLP body (quarters share W1/W2 staging in LDS),
// each quarter spin-waits (agent-acquire + s_sleep) until progress[b] > m.
// MLP consumption (252 blocks) >> FPS production rate, so MLP fully hides
// under FPS except the last ~2 chunks (~3 us tail). Then a manual single-use
// grid barrier (all NBLK<=256 blocks co-resident: 1 blk/CU by LDS+VGPR,
// serialized stream => all dispatched; timeout-guarded), then fused BN:
// block j owns channel(s) j (+254): deterministic double-accum stats kept in
// registers/LDS, apply in place. No separate launches, no stats round-trip.
//
// FPS correctness notes (unchanged from passing R4): key = (d_bits<<26) |
// (8191-pid)<<13 | pos; u64 max == (max d, then min ORIGINAL index) ==
// jnp.argmax first-occurrence. Skip proof: skip bucket iff dist(win,c) >
// sqrt(bd*1.0001)+rad => for all pts dist(win,pt) >= dist-rad > sqrt(bd) >=
// sqrt(d[k]) => fmin no-op, key unchanged. Updates are exact fmin =>
// order-free; counting-sort scatter nondeterminism is output-invariant.
// ---------------------------------------------------------------------------
__global__ __launch_bounds__(1024, 4) void fused_kernel(
    const float* __restrict__ xyz, const float* __restrict__ x,
    const float* __restrict__ W1, const float* __restrict__ b1,
    const float* __restrict__ W2, const float* __restrict__ b2,
    const float* __restrict__ gamma, const float* __restrict__ beta,
    float* __restrict__ new_xyz, float* __restrict__ outp,
    int* __restrict__ ws) {   // ws[0..1]=progress per batch, ws[2]=arrive, ws[3]=go
  __shared__ SmemU s;
  __shared__ double aS[16], aS2[16];
  __shared__ float bnb[2];

  const int blk = blockIdx.x;
  const int t = threadIdx.x;
  const int lane = t & 63;

  if (blk < FPSB) {
    // =========================== FPS (R4 core) ===========================
    const int b = blk;
    const int w = t >> 6;
    const float* xb = xyz + (size_t)b * N_ * 3;
    float* gdst = new_xyz + (size_t)b * M_ * 3;

    int* hist = (int*)s.f.d;   // sort scratch aliases s.f.d (dead until init)
    int* boff = hist + 512;
    int* wsum = boff + 512;

    // ---- counting sort by morton cell (SoA + u16 pid) ----
    if (t < 512) hist[t] = 0;
    if (t < 3) s.f.win[t] = 0ull;
    __syncthreads();
#pragma unroll
    for (int rr = 0; rr < 8; ++rr) {
      int i = rr * 1024 + t;
      float X = xb[i * 3 + 0], Y = xb[i * 3 + 1], Z = xb[i * 3 + 2];
      int ix = min(7, max(0, (int)(X * 8.0f)));
      int iy = min(7, max(0, (int)(Y * 8.0f)));
      int iz = min(7, max(0, (int)(Z * 8.0f)));
      atomicAdd(&hist[morton8(ix, iy, iz)], 1);
    }
    __syncthreads();
    {  // exclusive scan of 512 bins (8 active waves)
      int ov = (t < 512) ? hist[t] : 0;
      int v = ov;
#pragma unroll
      for (int off = 1; off < 64; off <<= 1) {
        int n = __shfl_up(v, off);
        if (lane >= off) v += n;
      }
      if (t < 512 && lane == 63) wsum[w] = v;
      __syncthreads();
      if (t == 0) {
        int acc = 0;
#pragma unroll
        for (int j = 0; j < 8; ++j) { int x0 = wsum[j]; wsum[j] = acc; acc += x0; }
      }
      __syncthreads();
      if (t < 512) boff[t] = v - ov + wsum[w];
    }
    __syncthreads();
#pragma unroll
    for (int rr = 0; rr < 8; ++rr) {
      int i = rr * 1024 + t;
      float X = xb[i * 3 + 0], Y = xb[i * 3 + 1], Z = xb[i * 3 + 2];
      int ix = min(7, max(0, (int)(X * 8.0f)));
      int iy = min(7, max(0, (int)(Y * 8.0f)));
      int iz = min(7, max(0, (int)(Z * 8.0f)));
      int pos = atomicAdd(&boff[morton8(ix, iy, iz)], 1);
      s.f.px[pos] = X; s.f.py[pos] = Y; s.f.pz[pos] = Z;
      s.f.pid[pos] = (unsigned short)i;
    }
    __syncthreads();  // sort done; scratch (in s.f.d) dead below

    // ---- per-bucket init: meta in registers, d + bkey in LDS ----
    float cx, cy, cz;
    unsigned maxlowk = 0;
    {
      float sx = 0.f, sy = 0.f, sz = 0.f;
#pragma unroll
      for (int k = 0; k < 8; ++k) {
        int p = 8 * t + k;
        sx += s.f.px[p]; sy += s.f.py[p]; sz += s.f.pz[p];
        unsigned pid = s.f.pid[p];
        unsigned lk = ((8191u - pid) << 13) | (unsigned)p;
        maxlowk = lk > maxlowk ? lk : maxlowk;
        s.f.d[p] = 1e10f;  // == f32(10000000000.0), matches jnp init exactly
      }
      cx = sx * 0.125f; cy = sy * 0.125f; cz = sz * 0.125f;
    }
    float r2m = 0.f;
#pragma unroll
    for (int k = 0; k < 8; ++k) {
      int p = 8 * t + k;
      float dx = s.f.px[p] - cx, dy = s.f.py[p] - cy, dz = s.f.pz[p] - cz;
      r2m = fmaxf(r2m, dx * dx + dy * dy + dz * dz);
    }
    const float rad = sqrtf(r2m) * 1.00002f + 1e-12f;
    unsigned long long kinit =
        ((unsigned long long)(unsigned)__float_as_int(1e10f) << 26) | maxlowk;
    s.f.bkey[t] = kinit;
    unsigned long long wmax = wave_max_u64_dpp(kinit);  // valid at lane 63
    float thrT = 3e38f;  // never skip until first update sets it

    int u = 0;
    for (int it = 0; it < M_; ++it) {
      if (lane == 63) atomicMax(&s.f.win[u], wmax);
      int nu = (u == 2) ? 0 : u + 1;
      if (t == 0) s.f.win[nu] = 0ull;  // clear slot used next iter (mod-3)
      __syncthreads();                 // the ONE barrier this iteration

      // ---- chunk flush: rows [it-128, it) from the ring (16x total) ----
      if ((it & (CHUNK - 1)) == 0 && it != 0) {
        if (t < CHUNK * 3) gdst[(size_t)(it - CHUNK) * 3 + t] = s.f.recent[t];
        if (t == 0 && it > CHUNK) {
          // rows < it-128 flushed one chunk ago; 128 barrier vmcnt-drains
          // since => complete in L2. Write back + agent-release.
          __threadfence();
          __hip_atomic_store(&ws[b], it - CHUNK, __ATOMIC_RELEASE,
                             __HIP_MEMORY_SCOPE_AGENT);
        }
      }

      unsigned long long wk = s.f.win[u];          // broadcast ds_read_b64
      u = nu;
      int winPos = (int)(unsigned)wk & 8191;
      float lx = s.f.px[winPos], ly = s.f.py[winPos], lz = s.f.pz[winPos];
      if (t == 0) {  // winner ring (LDS only; same-wave order vs flush reads)
        s.f.recent[(it & (CHUNK - 1)) * 3 + 0] = lx;
        s.f.recent[(it & (CHUNK - 1)) * 3 + 1] = ly;
        s.f.recent[(it & (CHUNK - 1)) * 3 + 2] = lz;
      }

      // ---- conservative per-bucket skip test (register meta) ----
      float ex = lx - cx, ey = ly - cy, ez = lz - cz;
      float dc2 = ex * ex + ey * ey + ez * ez;
      bool dirty = dc2 <= thrT;
      unsigned long long mask = __ballot(dirty);
      if (mask != 0ull) {
        int Dw = __popcll(mask);
        if (dirty) {
          int pre = __popcll(mask & ((1ull << lane) - 1ull));
          s.f.wlist[w][pre] = t;
        }
        asm volatile("s_waitcnt lgkmcnt(0)" ::: "memory");
        // FAT rounds: 32 buckets/round, 2 lanes/bucket, 4 pts/lane, b128 LDS
        int rounds = (Dw + 31) >> 5;
        for (int r = 0; r < rounds; ++r) {
          int gi = r * 32 + (lane >> 1);
          bool act = gi < Dw;
          int bkt = s.f.wlist[w][act ? gi : 0];
          int pb = bkt * 8 + (lane & 1) * 4;
          float4 X4 = *(const float4*)&s.f.px[pb];
          float4 Y4 = *(const float4*)&s.f.py[pb];
          float4 Z4 = *(const float4*)&s.f.pz[pb];
          float4 D4 = *(float4*)&s.f.d[pb];
          ushort4 P4 = *(const ushort4*)&s.f.pid[pb];
          unsigned long long bk = 0ull;
#define UPD(Xc, Yc, Zc, Dc, Pc, off)                                           \
          {                                                                    \
            float dist = sqdist_rn(Xc, Yc, Zc, lx, ly, lz);                    \
            float dm = fminf(Dc, dist); /* exact min: order-free, skip-safe */ \
            Dc = dm;                                                           \
            unsigned long long key =                                           \
                ((unsigned long long)(unsigned)__float_as_int(dm) << 26) |     \
                (((8191u - (unsigned)(Pc)) << 13) | (unsigned)(pb + (off)));   \
            if (key > bk) bk = key;                                            \
          }
          UPD(X4.x, Y4.x, Z4.x, D4.x, P4.x, 0)
          UPD(X4.y, Y4.y, Z4.y, D4.y, P4.y, 1)
          UPD(X4.z, Y4.z, Z4.z, D4.z, P4.z, 2)
          UPD(X4.w, Y4.w, Z4.w, D4.w, P4.w, 3)
#undef UPD
          if (act) *(float4*)&s.f.d[pb] = D4;
          {  // pair reduce (lanes 2i <-> 2i+1), all-VALU (quad_perm xor1)
            int klo = (int)(unsigned)bk, khi = (int)(unsigned)(bk >> 32);
            int olo = __builtin_amdgcn_update_dpp(klo, klo, 0xB1, 0xf, 0xf, false);
            int ohi = __builtin_amdgcn_update_dpp(khi, khi, 0xB1, 0xf, 0xf, false);
            unsigned long long ok =
                ((unsigned long long)(unsigned)ohi << 32) | (unsigned)olo;
            if (ok > bk) bk = ok;
          }
          if (act && !(lane & 1)) s.f.bkey[bkt] = bk;
        }
        asm volatile("s_waitcnt lgkmcnt(0)" ::: "memory");
        unsigned long long nk = s.f.bkey[t];
        if (dirty) {
          float bd = __int_as_float((int)(unsigned)(nk >> 26));
          float sr = sqrtf(bd * 1.0001f) + rad;  // margins dwarf ulp
          thrT = sr * sr;
        }
        wmax = wave_max_u64_dpp(nk);
      }
    }
    // ---- final flush: rows [M-128, M) + full release ----
    __syncthreads();
    if (t < CHUNK * 3) gdst[(size_t)(M_ - CHUNK) * 3 + t] = s.f.recent[t];
    __syncthreads();  // per-wave vmcnt(0) drain of all flush stores
    if (t == 0) {
      __threadfence();
      __hip_atomic_store(&ws[b], M_, __ATOMIC_RELEASE, __HIP_MEMORY_SCOPE_AGENT);
    }
  } else {
    // =========================== MLP workers ===========================
    const int quarter = t >> 8;   // 0..3, each = 4 consecutive waves
    const int tt = t & 255;
    const int wq = tt >> 6;       // wave within quarter
    MlpQuarter& Q4 = s.m.q[quarter];
    const float R2 = (float)(0.1 * 0.1);  // (float)(0.1*0.1) exactly

    for (int q = blk - FPSB; q < (B_ * M_) / 4; q += MLPB) {
      const int g = 4 * q + quarter;
      const int b = g >> 11;
      const int m = g & 2047;
      {  // gate on FPS progress (wave-uniform; acquire syncs new_xyz reads)
        int guard = 0;
        while (__hip_atomic_load(&ws[b], __ATOMIC_ACQUIRE,
                                 __HIP_MEMORY_SCOPE_AGENT) <= m) {
          __builtin_amdgcn_s_sleep(32);
          if (++guard > (1 << 21)) break;  // failsafe: never hang the GPU
        }
      }
      const float* xb = xyz + (size_t)b * N_ * 3;
      if (tt < 3) Q4.Q[tt] = new_xyz[(size_t)g * 3 + tt];
      __syncthreads();
      const float qx = Q4.Q[0], qy = Q4.Q[1], qz = Q4.Q[2];

      // ---- ball query: wave wq scans [wq*2048, +2048) in index order ----
      {
        int cnt = 0;
        const int cbeg = wq * 2048, cend = cbeg + 2048;
        for (int base = cbeg; base < cend; base += 64) {
          int p = base + lane;
          float d2 = sqdist_rn(qx, qy, qz, xb[p * 3 + 0], xb[p * 3 + 1], xb[p * 3 + 2]);
          bool valid = d2 < R2;
          unsigned long long mask = __ballot(valid);
          if (valid) {
            int pos = cnt + __popcll(mask & ((1ull << lane) - 1ull));
            if (pos < K_) Q4.WIdx[wq][pos] = p;
          }
          cnt += __popcll(mask);
          if (cnt >= K_) break;  // wave-uniform
        }
        if (lane == 0) Q4.WCnt[wq] = (cnt < K_) ? cnt : K_;
      }
      __syncthreads();
      if (tt < K_) {
        int c0 = Q4.WCnt[0], c1 = Q4.WCnt[1], c2 = Q4.WCnt[2], c3 = Q4.WCnt[3];
        int s1 = c0 + c1, s2 = s1 + c2, s3 = s2 + c3;
        int j = tt, idx;
        if (j < c0) idx = Q4.WIdx[0][j];
        else if (j < s1) idx = Q4.WIdx[1][j - c0];
        else if (j < s2) idx = Q4.WIdx[2][j - s1];
        else if (j < s3) idx = Q4.WIdx[3][j - s2];
        else {
          int fw = c0 ? 0 : (c1 ? 1 : (c2 ? 2 : 3));
          idx = (s3 > 0) ? Q4.WIdx[fw][0] : 0;  // fill with first valid index
        }
        Q4.Idx[j] = idx;
      }
      __syncthreads();

      // ---- grouping: rel coords + features into GRed (32 x 69 padded) ----
      if (tt < K_) {
        int id = Q4.Idx[tt];
        Q4.GRed[tt * 69 + 0] = xb[id * 3 + 0] - qx;
        Q4.GRed[tt * 69 + 1] = xb[id * 3 + 1] - qy;
        Q4.GRed[tt * 69 + 2] = xb[id * 3 + 2] - qz;
      }
      {
        int r = tt & 31;
        int c0 = (tt >> 5) * 8;
        int id = Q4.Idx[r];
        const float* xf = x + ((size_t)b * C0_ + c0) * N_ + id;
#pragma unroll
        for (int j = 0; j < 8; ++j) Q4.GRed[r * 69 + 3 + c0 + j] = xf[(size_t)j * N_];
      }
      // W1 staging: shared across quarters, all 1024 threads
      for (int i = t; i < C1_ * CIN_; i += 1024) {
        s.m.U[(i / CIN_) * 69 + (i % CIN_)] = W1[i];
      }
      __syncthreads();

      const int ol = tt & 31;  // output-lane: o = ol + 32*j
      const int rg = tt >> 5;  // row group: rows rg*4 .. rg*4+3

      // ---- layer 1: h1 = relu(G @ W1^T + b1), 4 rows x 4 outs / thread ----
      float acc[4][4] = {{0.f}};
      for (int c = 0; c < CIN_; ++c) {
        float gv[4], wv[4];
#pragma unroll
        for (int i = 0; i < 4; ++i) gv[i] = Q4.GRed[(rg * 4 + i) * 69 + c];
#pragma unroll
        for (int j = 0; j < 4; ++j) wv[j] = s.m.U[(ol + 32 * j) * 69 + c];
#pragma unroll
        for (int i = 0; i < 4; ++i)
#pragma unroll
          for (int j = 0; j < 4; ++j) acc[i][j] += gv[i] * wv[j];
      }
#pragma unroll
      for (int j = 0; j < 4; ++j) {
        float bias = b1[ol + 32 * j];
#pragma unroll
        for (int i = 0; i < 4; ++i) {
          float v = acc[i][j] + bias;
          Q4.H1[(rg * 4 + i) * 132 + ol + 32 * j] = fmaxf(v, 0.0f);
        }
      }

      // ---- layer 2: h2 = h1 @ W2^T, 4 rows x 8 outs / thread ----
      float acc2[4][8] = {{0.f}};
      for (int ct = 0; ct < 4; ++ct) {
        __syncthreads();  // U reuse safe; (ct==0) also covers H1 writes
        const float4* w4 = (const float4*)(W2 + (size_t)tt * C1_ + ct * 32);
#pragma unroll
        for (int jj2 = 0; jj2 < 2; ++jj2) {  // quarters split the 8 float4s
          int jj = quarter * 2 + jj2;
          float4 v = w4[jj];
          s.m.U[(jj * 4 + 0) * 256 + tt] = v.x;
          s.m.U[(jj * 4 + 1) * 256 + tt] = v.y;
          s.m.U[(jj * 4 + 2) * 256 + tt] = v.z;
          s.m.U[(jj * 4 + 3) * 256 + tt] = v.w;
        }
        __syncthreads();
        for (int cc = 0; cc < 32; ++cc) {
          float h[4], wv[8];
#pragma unroll
          for (int i = 0; i < 4; ++i) h[i] = Q4.H1[(rg * 4 + i) * 132 + ct * 32 + cc];
#pragma unroll
          for (int j = 0; j < 8; ++j) wv[j] = s.m.U[cc * 256 + ol + 32 * j];
#pragma unroll
          for (int i = 0; i < 4; ++i)
#pragma unroll
            for (int j = 0; j < 8; ++j) acc2[i][j] += h[i] * wv[j];
        }
      }

      // ---- max over K, + b2 (max(x)+c == max(x+c): RN is monotone) ----
      __syncthreads();  // group tile dead; reuse GRed as reduction buffer
#pragma unroll
      for (int j = 0; j < 8; ++j) {
        float pm = acc2[0][j];
#pragma unroll
        for (int i = 1; i < 4; ++i) pm = fmaxf(pm, acc2[i][j]);
        Q4.GRed[rg * 256 + ol + 32 * j] = pm;
      }
      __syncthreads();
      {
        int o = tt;
        float v = Q4.GRed[o];
#pragma unroll
        for (int gg = 1; gg < 8; ++gg) v = fmaxf(v, Q4.GRed[gg * 256 + o]);
        v += b2[o];
        outp[((size_t)(b * C2_ + o)) * M_ + m] = v;  // (B,C2,M) pre-BN
      }
      __syncthreads();  // protect GRed/U reuse by next job
    }
  }

  // ======================= manual grid barrier =======================
  // All NBLK blocks are co-resident (1 blk/CU, NBLK<=256, serialized
  // stream) so a single-use arrive/go barrier is safe; timeout-guarded.
  __syncthreads();
  if (t == 0) {
    __threadfence();  // publish this block's outp/new_xyz stores (wbl2)
    int arrived = __hip_atomic_fetch_add(&ws[2], 1, __ATOMIC_ACQ_REL,
                                         __HIP_MEMORY_SCOPE_AGENT) + 1;
    if (arrived == NBLK)
      __hip_atomic_store(&ws[3], 1, __ATOMIC_RELEASE, __HIP_MEMORY_SCOPE_AGENT);
    int guard = 0;
    while (__hip_atomic_load(&ws[3], __ATOMIC_ACQUIRE,
                             __HIP_MEMORY_SCOPE_AGENT) == 0) {
      __builtin_amdgcn_s_sleep(32);
      if (++guard > (1 << 21)) break;  // failsafe
    }
  }
  __syncthreads();

  // =========================== fused BN ===========================
  // Block j owns channel j (blocks 0,1 also take 254,255). Deterministic
  // double accumulation; stats never leave the block.
  for (int ch = blk; ch < C2_; ch += NBLK) {
    double sS = 0.0, sS2 = 0.0;
    for (int bb = 0; bb < B_; ++bb) {
      const float* p = outp + ((size_t)(bb * C2_ + ch)) * M_;
      for (int i = t; i < M_; i += 1024) {
        float v = p[i];
        sS += (double)v;
        sS2 += (double)v * (double)v;
      }
    }
#pragma unroll
    for (int off = 32; off > 0; off >>= 1) {
      sS += __shfl_xor(sS, off);
      sS2 += __shfl_xor(sS2, off);
    }
    if (lane == 0) { aS[t >> 6] = sS; aS2[t >> 6] = sS2; }
    __syncthreads();
    if (t == 0) {
      double S = 0.0, S2 = 0.0;
#pragma unroll
      for (int j = 0; j < 16; ++j) { S += aS[j]; S2 += aS2[j]; }
      double mean = S / (double)(B_ * M_);
      double var = S2 / (double)(B_ * M_) - mean * mean;
      float rstd = 1.0f / sqrtf((float)var + 1e-5f);
      bnb[0] = (float)mean;
      bnb[1] = gamma[ch] * rstd;
    }
    __syncthreads();
    {
      float mean = bnb[0], scale = bnb[1], bt = beta[ch];
      int bb = t >> 9, i = t & 511;  // 1024 thr = 2 batches x 512 float4
      float4* p4 = (float4*)(outp + ((size_t)(bb * C2_ + ch)) * M_);
      float4 v = p4[i];
      v.x = (v.x - mean) * scale + bt;
      v.y = (v.y - mean) * scale + bt;
      v.z = (v.z - mean) * scale + bt;
      v.w = (v.w - mean) * scale + bt;
      p4[i] = v;
    }
    __syncthreads();  // protect aS/bnb reuse (blocks doing 2 channels)
  }
}

// ---------------------------------------------------------------------------
extern "C" void kernel_launch(void* const* d_in, const int* in_sizes, int n_in,
                              void* d_out, int out_size, void* d_ws, size_t ws_size,
                              hipStream_t stream) {
  const float* xyz   = (const float*)d_in[0];
  const float* x     = (const float*)d_in[1];
  const float* W1    = (const float*)d_in[2];
  const float* b1    = (const float*)d_in[3];
  const float* W2    = (const float*)d_in[4];
  const float* b2    = (const float*)d_in[5];
  const float* gamma = (const float*)d_in[6];
  const float* beta  = (const float*)d_in[7];

  float* new_xyz = (float*)d_out;                       // (B, M, 3)
  float* outp    = (float*)d_out + (size_t)B_ * M_ * 3; // (B, C2, M)
  int*   ws      = (int*)d_ws;                          // progress[2], arrive, go

  hipMemsetAsync(d_ws, 0, 16, stream);
  fused_kernel<<<NBLK, 1024, 0, stream>>>(xyz, x, W1, b1, W2, b2, gamma, beta,
                                          new_xyz, outp, ws);
}

// Round 7
// 2598.776 us; speedup vs baseline: 1.1148x; 1.1148x over previous
//
#include <hip/hip_runtime.h>
#include <cstdint>
#include <cstddef>

#define B_    2
#define N_    8192
#define M_    2048
#define K_    32
#define C0_   64
#define C1_   128
#define C2_   256
#define CIN_  67
#define CHUNK 128
#define FPSB  2
#define MLPB  64           // MLP worker blocks (key change: 252 -> 64)
#define NBLK  (FPSB + MLPB)  // 66 blocks total, ~26% of CUs — keep clocks high

// Exact-match distance: reference computes sum((a-b)**2, axis=-1) in f32 as
// ((dx^2 + dy^2) + dz^2) with no FMA contraction. _rn intrinsics forbid
// contract-fast fma fusion (would flip argmax / radius-boundary decisions).
__device__ __forceinline__ float sqdist_rn(float ax, float ay, float az,
                                           float bx, float by, float bz) {
  float dx = __fsub_rn(ax, bx);
  float dy = __fsub_rn(ay, by);
  float dz = __fsub_rn(az, bz);
  return __fadd_rn(__fadd_rn(__fmul_rn(dx, dx), __fmul_rn(dy, dy)),
                   __fmul_rn(dz, dz));
}

__device__ __forceinline__ int morton8(int ix, int iy, int iz) {
  int m = 0;
#pragma unroll
  for (int b = 0; b < 3; ++b) {
    m |= (((ix >> b) & 1) << (3 * b + 2)) | (((iy >> b) & 1) << (3 * b + 1)) |
         (((iz >> b) & 1) << (3 * b + 0));
  }
  return m;
}

// u64 max across the wave via paired DPP (row_shr 1/2/4/8, row_bcast 15/31);
// cumulative max lands in lane 63. Exact tie-break is baked into the key.
__device__ __forceinline__ unsigned long long wave_max_u64_dpp(unsigned long long k) {
#define FPS_STEP(ctrl)                                                         \
  {                                                                            \
    int klo = (int)(unsigned)k, khi = (int)(unsigned)(k >> 32);                \
    int olo = __builtin_amdgcn_update_dpp(klo, klo, ctrl, 0xf, 0xf, false);    \
    int ohi = __builtin_amdgcn_update_dpp(khi, khi, ctrl, 0xf, 0xf, false);    \
    unsigned long long ok =                                                    \
        ((unsigned long long)(unsigned)ohi << 32) | (unsigned)olo;             \
    if (ok > k) k = ok;                                                        \
  }
  FPS_STEP(0x111)  // row_shr:1
  FPS_STEP(0x112)  // row_shr:2
  FPS_STEP(0x114)  // row_shr:4
  FPS_STEP(0x118)  // row_shr:8
  FPS_STEP(0x142)  // row_bcast:15
  FPS_STEP(0x143)  // row_bcast:31
#undef FPS_STEP
  return k;
}

// ---------------------------------------------------------------------------
// Shared-memory union: FPS layout (blocks 0-1) vs quad-MLP layout (blocks 2+).
// ---------------------------------------------------------------------------
struct SmemFps {
  float px[N_];                       // 32 KiB sorted x
  float py[N_];                       // 32 KiB sorted y
  float pz[N_];                       // 32 KiB sorted z
  float d[N_];                        // 32 KiB min dists (sort scratch union)
  unsigned short pid[N_];             // 16 KiB original ids
  unsigned long long bkey[N_ / 8];    //  8 KiB per-bucket argmax key
  int wlist[16][64];                  //  4 KiB per-wave dirty lists
  unsigned long long win[3];          // rotating winner slots (mod-3 protocol)
  float recent[CHUNK * 3];            // 1.5 KiB winner ring (row-major [128][3])
};
struct MlpQuarter {
  float GRed[32 * 69];                // group tile; reused as 8x256 max-red
  float H1[32 * 132];
  int WIdx[4][K_];
  int WCnt[4];
  int Idx[K_];
  float Q[4];
};
struct SmemMlp {
  float U[128 * 69];                  // W1 staged; reused as 32x256 W2 tile (shared by quarters)
  MlpQuarter q[4];
};
union SmemU {
  SmemFps f;
  SmemMlp m;
};

// ---------------------------------------------------------------------------
// ONE fused kernel. Blocks 0-1: FPS (R4 core) with the 128-row LDS winner
// ring flushed to new_xyz once per CHUNK + threadfence + agent-release of
// progress[b] (release lags one chunk: flush stores provably drained by the
// 128 intervening barrier vmcnt-drains). Blocks 2..65: 4x the proven
// 256-thread MLP body. R6 post-mortem: 252 workers (99% CU residency + 4032
// agent-acquire spinners) slowed the latency-bound FPS loop ~22% — footprint
// now 64 workers (~26% CUs) with s_sleep(127) polls. Jobs are BATCH-
// INTERLEAVED (job k: batch=k&1, qi=(blk-2)+(k>>1)*64 -> m=4qi+quarter) so a
// block's job list is monotone in m; only its last ~2 jobs gate on the final
// release (R6's batch-sequential list stalled released batch-1 work behind a
// late batch-0 gate). Then a manual single-use grid barrier (all 66 blocks
// co-resident: 1 blk/CU by LDS, 66 <= 256 CUs; timeout-guarded), then fused
// BN (block owns channels blk, blk+66, ...): deterministic double-accum
// stats in registers/LDS, apply in place.
//
// FPS correctness (unchanged from passing R4/R6): key = (d_bits<<26) |
// (8191-pid)<<13 | pos; u64 max == (max d, then min ORIGINAL index) ==
// jnp.argmax first-occurrence. Skip proof: skip bucket iff dist(win,c) >
// sqrt(bd*1.0001)+rad => for all pts dist(win,pt) >= dist-rad > sqrt(bd) >=
// sqrt(d[k]) => fmin no-op, key unchanged. Updates are exact fmin =>
// order-free; counting-sort scatter nondeterminism is output-invariant.
// ---------------------------------------------------------------------------
__global__ __launch_bounds__(1024, 4) void fused_kernel(
    const float* __restrict__ xyz, const float* __restrict__ x,
    const float* __restrict__ W1, const float* __restrict__ b1,
    const float* __restrict__ W2, const float* __restrict__ b2,
    const float* __restrict__ gamma, const float* __restrict__ beta,
    float* __restrict__ new_xyz, float* __restrict__ outp,
    int* __restrict__ ws) {   // ws[0..1]=progress per batch, ws[2]=arrive, ws[3]=go
  __shared__ SmemU s;
  __shared__ double aS[16], aS2[16];
  __shared__ float bnb[2];

  const int blk = blockIdx.x;
  const int t = threadIdx.x;
  const int lane = t & 63;

  if (blk < FPSB) {
    // =========================== FPS (R4 core) ===========================
    const int b = blk;
    const int w = t >> 6;
    const float* xb = xyz + (size_t)b * N_ * 3;
    float* gdst = new_xyz + (size_t)b * M_ * 3;

    int* hist = (int*)s.f.d;   // sort scratch aliases s.f.d (dead until init)
    int* boff = hist + 512;
    int* wsum = boff + 512;

    // ---- counting sort by morton cell (SoA + u16 pid) ----
    if (t < 512) hist[t] = 0;
    if (t < 3) s.f.win[t] = 0ull;
    __syncthreads();
#pragma unroll
    for (int rr = 0; rr < 8; ++rr) {
      int i = rr * 1024 + t;
      float X = xb[i * 3 + 0], Y = xb[i * 3 + 1], Z = xb[i * 3 + 2];
      int ix = min(7, max(0, (int)(X * 8.0f)));
      int iy = min(7, max(0, (int)(Y * 8.0f)));
      int iz = min(7, max(0, (int)(Z * 8.0f)));
      atomicAdd(&hist[morton8(ix, iy, iz)], 1);
    }
    __syncthreads();
    {  // exclusive scan of 512 bins (8 active waves)
      int ov = (t < 512) ? hist[t] : 0;
      int v = ov;
#pragma unroll
      for (int off = 1; off < 64; off <<= 1) {
        int n = __shfl_up(v, off);
        if (lane >= off) v += n;
      }
      if (t < 512 && lane == 63) wsum[w] = v;
      __syncthreads();
      if (t == 0) {
        int acc = 0;
#pragma unroll
        for (int j = 0; j < 8; ++j) { int x0 = wsum[j]; wsum[j] = acc; acc += x0; }
      }
      __syncthreads();
      if (t < 512) boff[t] = v - ov + wsum[w];
    }
    __syncthreads();
#pragma unroll
    for (int rr = 0; rr < 8; ++rr) {
      int i = rr * 1024 + t;
      float X = xb[i * 3 + 0], Y = xb[i * 3 + 1], Z = xb[i * 3 + 2];
      int ix = min(7, max(0, (int)(X * 8.0f)));
      int iy = min(7, max(0, (int)(Y * 8.0f)));
      int iz = min(7, max(0, (int)(Z * 8.0f)));
      int pos = atomicAdd(&boff[morton8(ix, iy, iz)], 1);
      s.f.px[pos] = X; s.f.py[pos] = Y; s.f.pz[pos] = Z;
      s.f.pid[pos] = (unsigned short)i;
    }
    __syncthreads();  // sort done; scratch (in s.f.d) dead below

    // ---- per-bucket init: meta in registers, d + bkey in LDS ----
    float cx, cy, cz;
    unsigned maxlowk = 0;
    {
      float sx = 0.f, sy = 0.f, sz = 0.f;
#pragma unroll
      for (int k = 0; k < 8; ++k) {
        int p = 8 * t + k;
        sx += s.f.px[p]; sy += s.f.py[p]; sz += s.f.pz[p];
        unsigned pid = s.f.pid[p];
        unsigned lk = ((8191u - pid) << 13) | (unsigned)p;
        maxlowk = lk > maxlowk ? lk : maxlowk;
        s.f.d[p] = 1e10f;  // == f32(10000000000.0), matches jnp init exactly
      }
      cx = sx * 0.125f; cy = sy * 0.125f; cz = sz * 0.125f;
    }
    float r2m = 0.f;
#pragma unroll
    for (int k = 0; k < 8; ++k) {
      int p = 8 * t + k;
      float dx = s.f.px[p] - cx, dy = s.f.py[p] - cy, dz = s.f.pz[p] - cz;
      r2m = fmaxf(r2m, dx * dx + dy * dy + dz * dz);
    }
    const float rad = sqrtf(r2m) * 1.00002f + 1e-12f;
    unsigned long long kinit =
        ((unsigned long long)(unsigned)__float_as_int(1e10f) << 26) | maxlowk;
    s.f.bkey[t] = kinit;
    unsigned long long wmax = wave_max_u64_dpp(kinit);  // valid at lane 63
    float thrT = 3e38f;  // never skip until first update sets it

    int u = 0;
    for (int it = 0; it < M_; ++it) {
      if (lane == 63) atomicMax(&s.f.win[u], wmax);
      int nu = (u == 2) ? 0 : u + 1;
      if (t == 0) s.f.win[nu] = 0ull;  // clear slot used next iter (mod-3)
      __syncthreads();                 // the ONE barrier this iteration

      // ---- chunk flush: rows [it-128, it) from the ring (16x total) ----
      if ((it & (CHUNK - 1)) == 0 && it != 0) {
        if (t < CHUNK * 3) gdst[(size_t)(it - CHUNK) * 3 + t] = s.f.recent[t];
        if (t == 0 && it > CHUNK) {
          // rows < it-128 flushed one chunk ago; 128 barrier vmcnt-drains
          // since => complete in L2. Write back + agent-release.
          __threadfence();
          __hip_atomic_store(&ws[b], it - CHUNK, __ATOMIC_RELEASE,
                             __HIP_MEMORY_SCOPE_AGENT);
        }
      }

      unsigned long long wk = s.f.win[u];          // broadcast ds_read_b64
      u = nu;
      int winPos = (int)(unsigned)wk & 8191;
      float lx = s.f.px[winPos], ly = s.f.py[winPos], lz = s.f.pz[winPos];
      if (t == 0) {  // winner ring (LDS only; same-wave order vs flush reads)
        s.f.recent[(it & (CHUNK - 1)) * 3 + 0] = lx;
        s.f.recent[(it & (CHUNK - 1)) * 3 + 1] = ly;
        s.f.recent[(it & (CHUNK - 1)) * 3 + 2] = lz;
      }

      // ---- conservative per-bucket skip test (register meta) ----
      float ex = lx - cx, ey = ly - cy, ez = lz - cz;
      float dc2 = ex * ex + ey * ey + ez * ez;
      bool dirty = dc2 <= thrT;
      unsigned long long mask = __ballot(dirty);
      if (mask != 0ull) {
        int Dw = __popcll(mask);
        if (dirty) {
          int pre = __popcll(mask & ((1ull << lane) - 1ull));
          s.f.wlist[w][pre] = t;
        }
        asm volatile("s_waitcnt lgkmcnt(0)" ::: "memory");
        // FAT rounds: 32 buckets/round, 2 lanes/bucket, 4 pts/lane, b128 LDS
        int rounds = (Dw + 31) >> 5;
        for (int r = 0; r < rounds; ++r) {
          int gi = r * 32 + (lane >> 1);
          bool act = gi < Dw;
          int bkt = s.f.wlist[w][act ? gi : 0];
          int pb = bkt * 8 + (lane & 1) * 4;
          float4 X4 = *(const float4*)&s.f.px[pb];
          float4 Y4 = *(const float4*)&s.f.py[pb];
          float4 Z4 = *(const float4*)&s.f.pz[pb];
          float4 D4 = *(float4*)&s.f.d[pb];
          ushort4 P4 = *(const ushort4*)&s.f.pid[pb];
          unsigned long long bk = 0ull;
#define UPD(Xc, Yc, Zc, Dc, Pc, off)                                           \
          {                                                                    \
            float dist = sqdist_rn(Xc, Yc, Zc, lx, ly, lz);                    \
            float dm = fminf(Dc, dist); /* exact min: order-free, skip-safe */ \
            Dc = dm;                                                           \
            unsigned long long key =                                           \
                ((unsigned long long)(unsigned)__float_as_int(dm) << 26) |     \
                (((8191u - (unsigned)(Pc)) << 13) | (unsigned)(pb + (off)));   \
            if (key > bk) bk = key;                                            \
          }
          UPD(X4.x, Y4.x, Z4.x, D4.x, P4.x, 0)
          UPD(X4.y, Y4.y, Z4.y, D4.y, P4.y, 1)
          UPD(X4.z, Y4.z, Z4.z, D4.z, P4.z, 2)
          UPD(X4.w, Y4.w, Z4.w, D4.w, P4.w, 3)
#undef UPD
          if (act) *(float4*)&s.f.d[pb] = D4;
          {  // pair reduce (lanes 2i <-> 2i+1), all-VALU (quad_perm xor1)
            int klo = (int)(unsigned)bk, khi = (int)(unsigned)(bk >> 32);
            int olo = __builtin_amdgcn_update_dpp(klo, klo, 0xB1, 0xf, 0xf, false);
            int ohi = __builtin_amdgcn_update_dpp(khi, khi, 0xB1, 0xf, 0xf, false);
            unsigned long long ok =
                ((unsigned long long)(unsigned)ohi << 32) | (unsigned)olo;
            if (ok > bk) bk = ok;
          }
          if (act && !(lane & 1)) s.f.bkey[bkt] = bk;
        }
        asm volatile("s_waitcnt lgkmcnt(0)" ::: "memory");
        unsigned long long nk = s.f.bkey[t];
        if (dirty) {
          float bd = __int_as_float((int)(unsigned)(nk >> 26));
          float sr = sqrtf(bd * 1.0001f) + rad;  // margins dwarf ulp
          thrT = sr * sr;
        }
        wmax = wave_max_u64_dpp(nk);
      }
    }
    // ---- final flush: rows [M-128, M) + full release ----
    __syncthreads();
    if (t < CHUNK * 3) gdst[(size_t)(M_ - CHUNK) * 3 + t] = s.f.recent[t];
    __syncthreads();  // per-wave vmcnt(0) drain of all flush stores
    if (t == 0) {
      __threadfence();
      __hip_atomic_store(&ws[b], M_, __ATOMIC_RELEASE, __HIP_MEMORY_SCOPE_AGENT);
    }
  } else {
    // =========================== MLP workers ===========================
    const int quarter = t >> 8;   // 0..3, each = 4 consecutive waves
    const int tt = t & 255;
    const int wq = tt >> 6;       // wave within quarter
    MlpQuarter& Q4 = s.m.q[quarter];
    const float R2 = (float)(0.1 * 0.1);  // (float)(0.1*0.1) exactly

    // Batch-interleaved static job list: monotone in m, so only the last ~2
    // jobs gate on the final FPS release.
    for (int k = 0; k < B_ * (512 / MLPB); ++k) {   // 16 jobs/block
      const int bb = k & 1;                          // batch
      const int qi = (blk - FPSB) + (k >> 1) * MLPB; // quartet in batch, <512
      const int m = 4 * qi + quarter;                // centroid row
      const int g = bb * M_ + m;                     // global centroid id
      {  // gate on FPS progress (wave-uniform; acquire syncs new_xyz reads)
        int guard = 0;
        while (__hip_atomic_load(&ws[bb], __ATOMIC_ACQUIRE,
                                 __HIP_MEMORY_SCOPE_AGENT) <= m) {
          __builtin_amdgcn_s_sleep(127);
          if (++guard > (1 << 20)) break;  // failsafe: never hang the GPU
        }
      }
      const float* xb = xyz + (size_t)bb * N_ * 3;
      if (tt < 3) Q4.Q[tt] = new_xyz[(size_t)g * 3 + tt];
      __syncthreads();
      const float qx = Q4.Q[0], qy = Q4.Q[1], qz = Q4.Q[2];

      // ---- ball query: wave wq scans [wq*2048, +2048) in index order ----
      {
        int cnt = 0;
        const int cbeg = wq * 2048, cend = cbeg + 2048;
        for (int base = cbeg; base < cend; base += 64) {
          int p = base + lane;
          float d2 = sqdist_rn(qx, qy, qz, xb[p * 3 + 0], xb[p * 3 + 1], xb[p * 3 + 2]);
          bool valid = d2 < R2;
          unsigned long long mask = __ballot(valid);
          if (valid) {
            int pos = cnt + __popcll(mask & ((1ull << lane) - 1ull));
            if (pos < K_) Q4.WIdx[wq][pos] = p;
          }
          cnt += __popcll(mask);
          if (cnt >= K_) break;  // wave-uniform
        }
        if (lane == 0) Q4.WCnt[wq] = (cnt < K_) ? cnt : K_;
      }
      __syncthreads();
      if (tt < K_) {
        int c0 = Q4.WCnt[0], c1 = Q4.WCnt[1], c2 = Q4.WCnt[2], c3 = Q4.WCnt[3];
        int s1 = c0 + c1, s2 = s1 + c2, s3 = s2 + c3;
        int j = tt, idx;
        if (j < c0) idx = Q4.WIdx[0][j];
        else if (j < s1) idx = Q4.WIdx[1][j - c0];
        else if (j < s2) idx = Q4.WIdx[2][j - s1];
        else if (j < s3) idx = Q4.WIdx[3][j - s2];
        else {
          int fw = c0 ? 0 : (c1 ? 1 : (c2 ? 2 : 3));
          idx = (s3 > 0) ? Q4.WIdx[fw][0] : 0;  // fill with first valid index
        }
        Q4.Idx[j] = idx;
      }
      __syncthreads();

      // ---- grouping: rel coords + features into GRed (32 x 69 padded) ----
      if (tt < K_) {
        int id = Q4.Idx[tt];
        Q4.GRed[tt * 69 + 0] = xb[id * 3 + 0] - qx;
        Q4.GRed[tt * 69 + 1] = xb[id * 3 + 1] - qy;
        Q4.GRed[tt * 69 + 2] = xb[id * 3 + 2] - qz;
      }
      {
        int r = tt & 31;
        int c0 = (tt >> 5) * 8;
        int id = Q4.Idx[r];
        const float* xf = x + ((size_t)bb * C0_ + c0) * N_ + id;
#pragma unroll
        for (int j = 0; j < 8; ++j) Q4.GRed[r * 69 + 3 + c0 + j] = xf[(size_t)j * N_];
      }
      // W1 staging: shared across quarters, all 1024 threads
      for (int i = t; i < C1_ * CIN_; i += 1024) {
        s.m.U[(i / CIN_) * 69 + (i % CIN_)] = W1[i];
      }
      __syncthreads();

      const int ol = tt & 31;  // output-lane: o = ol + 32*j
      const int rg = tt >> 5;  // row group: rows rg*4 .. rg*4+3

      // ---- layer 1: h1 = relu(G @ W1^T + b1), 4 rows x 4 outs / thread ----
      float acc[4][4] = {{0.f}};
      for (int c = 0; c < CIN_; ++c) {
        float gv[4], wv[4];
#pragma unroll
        for (int i = 0; i < 4; ++i) gv[i] = Q4.GRed[(rg * 4 + i) * 69 + c];
#pragma unroll
        for (int j = 0; j < 4; ++j) wv[j] = s.m.U[(ol + 32 * j) * 69 + c];
#pragma unroll
        for (int i = 0; i < 4; ++i)
#pragma unroll
          for (int j = 0; j < 4; ++j) acc[i][j] += gv[i] * wv[j];
      }
#pragma unroll
      for (int j = 0; j < 4; ++j) {
        float bias = b1[ol + 32 * j];
#pragma unroll
        for (int i = 0; i < 4; ++i) {
          float v = acc[i][j] + bias;
          Q4.H1[(rg * 4 + i) * 132 + ol + 32 * j] = fmaxf(v, 0.0f);
        }
      }

      // ---- layer 2: h2 = h1 @ W2^T, 4 rows x 8 outs / thread ----
      float acc2[4][8] = {{0.f}};
      for (int ct = 0; ct < 4; ++ct) {
        __syncthreads();  // U reuse safe; (ct==0) also covers H1 writes
        const float4* w4 = (const float4*)(W2 + (size_t)tt * C1_ + ct * 32);
#pragma unroll
        for (int jj2 = 0; jj2 < 2; ++jj2) {  // quarters split the 8 float4s
          int jj = quarter * 2 + jj2;
          float4 v = w4[jj];
          s.m.U[(jj * 4 + 0) * 256 + tt] = v.x;
          s.m.U[(jj * 4 + 1) * 256 + tt] = v.y;
          s.m.U[(jj * 4 + 2) * 256 + tt] = v.z;
          s.m.U[(jj * 4 + 3) * 256 + tt] = v.w;
        }
        __syncthreads();
        for (int cc = 0; cc < 32; ++cc) {
          float h[4], wv[8];
#pragma unroll
          for (int i = 0; i < 4; ++i) h[i] = Q4.H1[(rg * 4 + i) * 132 + ct * 32 + cc];
#pragma unroll
          for (int j = 0; j < 8; ++j) wv[j] = s.m.U[cc * 256 + ol + 32 * j];
#pragma unroll
          for (int i = 0; i < 4; ++i)
#pragma unroll
            for (int j = 0; j < 8; ++j) acc2[i][j] += h[i] * wv[j];
        }
      }

      // ---- max over K, + b2 (max(x)+c == max(x+c): RN is monotone) ----
      __syncthreads();  // group tile dead; reuse GRed as reduction buffer
#pragma unroll
      for (int j = 0; j < 8; ++j) {
        float pm = acc2[0][j];
#pragma unroll
        for (int i = 1; i < 4; ++i) pm = fmaxf(pm, acc2[i][j]);
        Q4.GRed[rg * 256 + ol + 32 * j] = pm;
      }
      __syncthreads();
      {
        int o = tt;
        float v = Q4.GRed[o];
#pragma unroll
        for (int gg = 1; gg < 8; ++gg) v = fmaxf(v, Q4.GRed[gg * 256 + o]);
        v += b2[o];
        outp[((size_t)(bb * C2_ + o)) * M_ + m] = v;  // (B,C2,M) pre-BN
      }
      __syncthreads();  // protect GRed/U reuse by next job
    }
  }

  // ======================= manual grid barrier =======================
  // All NBLK blocks are co-resident (1 blk/CU, NBLK<=256, serialized
  // stream) so a single-use arrive/go barrier is safe; timeout-guarded.
  __syncthreads();
  if (t == 0) {
    __threadfence();  // publish this block's outp/new_xyz stores (wbl2)
    int arrived = __hip_atomic_fetch_add(&ws[2], 1, __ATOMIC_ACQ_REL,
                                         __HIP_MEMORY_SCOPE_AGENT) + 1;
    if (arrived == NBLK)
      __hip_atomic_store(&ws[3], 1, __ATOMIC_RELEASE, __HIP_MEMORY_SCOPE_AGENT);
    int guard = 0;
    while (__hip_atomic_load(&ws[3], __ATOMIC_ACQUIRE,
                             __HIP_MEMORY_SCOPE_AGENT) == 0) {
      __builtin_amdgcn_s_sleep(32);
      if (++guard > (1 << 21)) break;  // failsafe
    }
  }
  __syncthreads();

  // =========================== fused BN ===========================
  // Block j owns channels j, j+NBLK, ... Deterministic double accumulation;
  // stats never leave the block.
  for (int ch = blk; ch < C2_; ch += NBLK) {
    double sS = 0.0, sS2 = 0.0;
    for (int bb = 0; bb < B_; ++bb) {
      const float* p = outp + ((size_t)(bb * C2_ + ch)) * M_;
      for (int i = t; i < M_; i += 1024) {
        float v = p[i];
        sS += (double)v;
        sS2 += (double)v * (double)v;
      }
    }
#pragma unroll
    for (int off = 32; off > 0; off >>= 1) {
      sS += __shfl_xor(sS, off);
      sS2 += __shfl_xor(sS2, off);
    }
    if (lane == 0) { aS[t >> 6] = sS; aS2[t >> 6] = sS2; }
    __syncthreads();
    if (t == 0) {
      double S = 0.0, S2 = 0.0;
#pragma unroll
      for (int j = 0; j < 16; ++j) { S += aS[j]; S2 += aS2[j]; }
      double mean = S / (double)(B_ * M_);
      double var = S2 / (double)(B_ * M_) - mean * mean;
      float rstd = 1.0f / sqrtf((float)var + 1e-5f);
      bnb[0] = (float)mean;
      bnb[1] = gamma[ch] * rstd;
    }
    __syncthreads();
    {
      float mean = bnb[0], scale = bnb[1], bt = beta[ch];
      int bb = t >> 9, i = t & 511;  // 1024 thr = 2 batches x 512 float4
      float4* p4 = (float4*)(outp + ((size_t)(bb * C2_ + ch)) * M_);
      float4 v = p4[i];
      v.x = (v.x - mean) * scale + bt;
      v.y = (v.y - mean) * scale + bt;
      v.z = (v.z - mean) * scale + bt;
      v.w = (v.w - mean) * scale + bt;
      p4[i] = v;
    }
    __syncthreads();  // protect aS/bnb reuse across channel rounds
  }
}

// ---------------------------------------------------------------------------
extern "C" void kernel_launch(void* const* d_in, const int* in_sizes, int n_in,
                              void* d_out, int out_size, void* d_ws, size_t ws_size,
                              hipStream_t stream) {
  const float* xyz   = (const float*)d_in[0];
  const float* x     = (const float*)d_in[1];
  const float* W1    = (const float*)d_in[2];
  const float* b1    = (const float*)d_in[3];
  const float* W2    = (const float*)d_in[4];
  const float* b2    = (const float*)d_in[5];
  const float* gamma = (const float*)d_in[6];
  const float* beta  = (const float*)d_in[7];

  float* new_xyz = (float*)d_out;                       // (B, M, 3)
  float* outp    = (float*)d_out + (size_t)B_ * M_ * 3; // (B, C2, M)
  int*   ws      = (int*)d_ws;                          // progress[2], arrive, go

  hipMemsetAsync(d_ws, 0, 16, stream);
  fused_kernel<<<NBLK, 1024, 0, stream>>>(xyz, x, W1, b1, W2, b2, gamma, beta,
                                          new_xyz, outp, ws);
}